// Round 7
// baseline (288.347 us; speedup 1.0000x reference)
//
#include <hip/hip_runtime.h>
#include <hip/hip_bf16.h>

typedef unsigned short u16;
typedef __attribute__((ext_vector_type(8))) short short8;
typedef __attribute__((ext_vector_type(4))) float floatx4;

#define NROWS 8192
#define DIM 256
#define BM 128        // rows per block
#define BNT 128       // cols per col-tile
#define NCT 4         // col-tiles per block -> 512 cols
#define NKB 8         // K-steps (BK=32)
#define BK 32

__device__ __forceinline__ void atomicMinFloat(float* addr, float val) {
    if (val >= 0.0f) {
        atomicMin((int*)addr, __float_as_int(val));
    } else {
        atomicMax((unsigned int*)addr, __float_as_uint(val));
    }
}

__device__ __forceinline__ u16 f32_to_bf16_rne(float x) {
    unsigned int u = __float_as_uint(x);
    unsigned int r = (u + 0x7fffu + ((u >> 16) & 1u)) >> 16;
    return (u16)r;
}

// C(M) = -logp * exp(logp); quasiconcave in M => rowmin = min(C(minM), C(maxM)).
__device__ __forceinline__ float c_of_m(float m) {
    const float INV_SIG = 1.0f / 0.3f;
    const float KC = 0.28503427f;  // -ln(0.3) - 0.5*ln(2*pi)
    float z = (m - 1.0f) * INV_SIG;
    float logp = fmaf(-0.5f * z, z, KC);
    return -logp * __expf(logp);
}

// 16B async DMA global -> LDS. LDS dest is wave-uniform base + lane*16.
__device__ __forceinline__ void load16(const u16* g, u16* l) {
    __builtin_amdgcn_global_load_lds(
        (__attribute__((address_space(1))) void*)g,
        (__attribute__((address_space(3))) void*)l, 16, 0, 0);
}

// Normalize rows (L2-norm clamped at 1e-8), wave per row, float4 loads.
// blockIdx.y==0: X -> row-major Xn (consumed via LDS staging in the GEMM)
//                and out[] init to +inf.
// blockIdx.y==1: Y -> MFMA B-panel layout Ys: element (row r, k) at
//                ((p*8+kt)*64 + lq*16 + lm)*8 + j, p=r>>4, lm=r&15,
//                kt=k>>5, lq=(k>>3)&3, j=k&7. A wave's B-fragment load in
//                the GEMM is then base + lane*16B: one coalesced dwordx4.
__global__ __launch_bounds__(256) void normalize_kernel(const float* __restrict__ Ex,
                                                        const float* __restrict__ Ey,
                                                        u16* __restrict__ Xn,
                                                        u16* __restrict__ Ys,
                                                        float* __restrict__ out) {
    const int t = threadIdx.x;
    const int ln = t & 63;
    const int row = blockIdx.x * 4 + (t >> 6);
    const float* src = (blockIdx.y == 0) ? Ex : Ey;

    float4 v = *(const float4*)(src + (size_t)row * DIM + ln * 4);
    float s = fmaf(v.x, v.x, fmaf(v.y, v.y, fmaf(v.z, v.z, v.w * v.w)));
    #pragma unroll
    for (int m = 32; m >= 1; m >>= 1) s += __shfl_xor(s, m, 64);
    float inv = 1.0f / fmaxf(sqrtf(s), 1e-8f);

    ushort4 o;
    o.x = f32_to_bf16_rne(v.x * inv);
    o.y = f32_to_bf16_rne(v.y * inv);
    o.z = f32_to_bf16_rne(v.z * inv);
    o.w = f32_to_bf16_rne(v.w * inv);

    if (blockIdx.y == 0) {
        *(ushort4*)(Xn + (size_t)row * DIM + ln * 4) = o;
        if (ln == 0) out[row] = __uint_as_float(0x7f800000u);  // +inf
    } else {
        const int p = row >> 4;
        const int lm = row & 15;
        const int kt = ln >> 3;
        const int lq = (ln >> 1) & 3;
        const int j4 = (ln & 1) * 4;
        const size_t off = ((size_t)((p * NKB + kt) * 64 + lq * 16 + lm)) * 8 + j4;
        *(ushort4*)(Ys + off) = o;
    }
}

// Block = 128 rows x 512 cols. A (128x256, 64 KB) staged to LDS ONCE via
// global_load_lds (xor-swizzled -> conflict-free b128 reads), ONE barrier,
// then a 32-step K-loop with ZERO barriers: A fragments from LDS, B
// fragments loaded straight from the panel-layout Ys (L2-resident strip,
// see grid ordering) into a 1-step register double-buffer. No vmcnt(0)
// drains anywhere in the loop -- the R2/R6 per-step barrier chain is gone.
// Grid: b&63 = row-tile (fixed A set per XCD), b>>6 = colgroup (all XCDs
// sweep the same 256 KB B-strip together -> B loads are L2 hits).
__global__ __launch_bounds__(256, 2) void gemm_min_kernel(const u16* __restrict__ Xn,
                                                          const u16* __restrict__ Ys,
                                                          float* __restrict__ out) {
    __shared__ u16 As[NKB][BM * BK];  // 64 KB, full-K A

    const int tid = threadIdx.x;
    const int w = tid >> 6;
    const int lane = tid & 63;
    const int wr = w >> 1;
    const int wc = w & 1;
    const int lq = lane >> 4;
    const int lm = lane & 15;
    const int swz = (lm >> 1) & 3;

    const int b = blockIdx.x;
    const int rowStart = (b & 63) * BM;
    const int colPanBase = (b >> 6) * 32 + wc * 4;  // first of this wave's B panels

    // --- A prologue: stage full-K A tile, single barrier ---
    {
        const int s0 = w * 64 + lane;
        const int s1 = s0 + 256;
        const int r0 = s0 >> 2, p0 = (s0 & 3) ^ ((r0 >> 1) & 3);
        const int r1 = s1 >> 2, p1 = (s1 & 3) ^ ((r1 >> 1) & 3);
        const int go0 = r0 * DIM + p0 * 8;
        const int go1 = r1 * DIM + p1 * 8;
        const int lo0 = (w * 64) * 8;
        const int lo1 = (256 + w * 64) * 8;
        const u16* xb = Xn + (size_t)rowStart * DIM;
        #pragma unroll
        for (int kb = 0; kb < NKB; ++kb) {
            load16(xb + go0 + kb * BK, &As[kb][lo0]);
            load16(xb + go1 + kb * BK, &As[kb][lo1]);
        }
    }

    int aoff[4];
    #pragma unroll
    for (int rg = 0; rg < 4; ++rg)
        aoff[rg] = ((wr * 64 + rg * 16 + lm) * 4 + (lq ^ swz)) * 8;

    // B fragment pointers: panel p, chunk kt at Ys + p*4096 + kt*512 + lane*8.
    const u16* bp[4];
    #pragma unroll
    for (int cg = 0; cg < 4; ++cg)
        bp[cg] = Ys + (size_t)(colPanBase + cg) * (NKB * 64 * 8) + lane * 8;

    floatx4 mn4[4], mx4[4];
    #pragma unroll
    for (int rg = 0; rg < 4; ++rg) {
        mn4[rg] = (floatx4){3.4e38f, 3.4e38f, 3.4e38f, 3.4e38f};
        mx4[rg] = (floatx4){-3.4e38f, -3.4e38f, -3.4e38f, -3.4e38f};
    }

    __syncthreads();  // the ONLY barrier: A tile ready

    // B register double-buffer; preload (ct=0, kt=0).
    short8 bbuf[2][4];
    #pragma unroll
    for (int cg = 0; cg < 4; ++cg)
        bbuf[0][cg] = *(const short8*)(bp[cg]);

    #pragma unroll
    for (int ct = 0; ct < NCT; ++ct) {
        floatx4 acc[4][4];
        #pragma unroll
        for (int i = 0; i < 4; ++i)
            #pragma unroll
            for (int j = 0; j < 4; ++j)
                acc[i][j] = (floatx4){0.0f, 0.0f, 0.0f, 0.0f};

        #pragma unroll
        for (int kt = 0; kt < NKB; ++kt) {
            short8 a[4];
            #pragma unroll
            for (int rg = 0; rg < 4; ++rg)
                a[rg] = *(const short8*)(&As[kt][aoff[rg]]);

            // Prefetch next step's B (next kt, or next ct's kt=0) into the
            // other register buffer -- ~1 full step of latency slack, no waits
            // on the current MFMAs.
            if (kt < NKB - 1) {
                #pragma unroll
                for (int cg = 0; cg < 4; ++cg)
                    bbuf[(kt + 1) & 1][cg] =
                        *(const short8*)(bp[cg] + (ct * (NKB * 8) + (kt + 1)) * 512 / 8 * 8);
            } else if (ct < NCT - 1) {
                #pragma unroll
                for (int cg = 0; cg < 4; ++cg)
                    bbuf[0][cg] = *(const short8*)(bp[cg] + ((ct + 1) * (NKB * 8)) * 512);
            }

            #pragma unroll
            for (int rg = 0; rg < 4; ++rg)
                #pragma unroll
                for (int cg = 0; cg < 4; ++cg)
                    acc[rg][cg] = __builtin_amdgcn_mfma_f32_16x16x32_bf16(
                        a[rg], bbuf[kt & 1][cg], acc[rg][cg], 0, 0, 0);
        }

        // Fold this col-tile into register-carried row min/max.
        #pragma unroll
        for (int rg = 0; rg < 4; ++rg)
            #pragma unroll
            for (int cg = 0; cg < 4; ++cg)
                #pragma unroll
                for (int r = 0; r < 4; ++r) {
                    float m = acc[rg][cg][r];
                    mn4[rg][r] = fminf(mn4[rg][r], m);
                    mx4[rg][r] = fmaxf(mx4[rg][r], m);
                }
    }

    // Single epilogue: quad-lane reduce, eval C twice (quasiconcavity),
    // fire-and-forget atomicMin (no read guard -- R3 post-mortem).
    #pragma unroll
    for (int rg = 0; rg < 4; ++rg) {
        #pragma unroll
        for (int r = 0; r < 4; ++r) {
            float mn = mn4[rg][r];
            float mx = mx4[rg][r];
            #pragma unroll
            for (int mofs = 1; mofs < 16; mofs <<= 1) {
                mn = fminf(mn, __shfl_xor(mn, mofs, 64));
                mx = fmaxf(mx, __shfl_xor(mx, mofs, 64));
            }
            if (lm == 0) {
                float cmin = fminf(c_of_m(mn), c_of_m(mx));
                int row = rowStart + wr * 64 + rg * 16 + lq * 4 + r;
                atomicMinFloat(&out[row], cmin);
            }
        }
    }
}

extern "C" void kernel_launch(void* const* d_in, const int* in_sizes, int n_in,
                              void* d_out, int out_size, void* d_ws, size_t ws_size,
                              hipStream_t stream) {
    const float* Ex = (const float*)d_in[0];
    const float* Ey = (const float*)d_in[1];
    float* out = (float*)d_out;
    u16* Xn = (u16*)d_ws;                // 4 MB, row-major bf16
    u16* Ys = Xn + (size_t)NROWS * DIM;  // 4 MB, B-panel layout bf16

    hipLaunchKernelGGL(normalize_kernel, dim3(NROWS / 4, 2), dim3(256), 0, stream,
                       Ex, Ey, Xn, Ys, out);
    hipLaunchKernelGGL(gemm_min_kernel, dim3(64 * (NROWS / (NCT * BNT))), dim3(256), 0, stream,
                       Xn, Ys, out);
}

// Round 8
// 121.263 us; speedup vs baseline: 2.3779x; 2.3779x over previous
//
#include <hip/hip_runtime.h>
#include <hip/hip_bf16.h>

typedef unsigned short u16;
typedef __attribute__((ext_vector_type(8))) short short8;
typedef __attribute__((ext_vector_type(4))) float floatx4;

#define NROWS 8192
#define DIM 256
#define BM 128        // rows per block
#define NCT 4         // col-tiles (128 cols each) per block -> 512 cols
#define NKB 8         // K-steps per col-tile (BK=32)
#define BK 32

__device__ __forceinline__ void atomicMinFloat(float* addr, float val) {
    if (val >= 0.0f) {
        atomicMin((int*)addr, __float_as_int(val));
    } else {
        atomicMax((unsigned int*)addr, __float_as_uint(val));
    }
}

__device__ __forceinline__ u16 f32_to_bf16_rne(float x) {
    unsigned int u = __float_as_uint(x);
    unsigned int r = (u + 0x7fffu + ((u >> 16) & 1u)) >> 16;
    return (u16)r;
}

// C(M) = -logp * exp(logp); quasiconcave in M => rowmin = min(C(minM), C(maxM)).
__device__ __forceinline__ float c_of_m(float m) {
    const float INV_SIG = 1.0f / 0.3f;
    const float KC = 0.28503427f;  // -ln(0.3) - 0.5*ln(2*pi)
    float z = (m - 1.0f) * INV_SIG;
    float logp = fmaf(-0.5f * z, z, KC);
    return -logp * __expf(logp);
}

// 16B async DMA global -> LDS. LDS dest is wave-uniform base + lane*16.
__device__ __forceinline__ void load16(const u16* g, u16* l) {
    __builtin_amdgcn_global_load_lds(
        (__attribute__((address_space(1))) void*)g,
        (__attribute__((address_space(3))) void*)l, 16, 0, 0);
}

// Normalize rows (L2-norm clamped at 1e-8), wave per row, float4 loads.
// blockIdx.y==0: X -> row-major Xn (GEMM stages it to LDS) + out[] init.
// blockIdx.y==1: Y -> MFMA B-panel layout Ys: element (row r, k) at
//   ((p*8+kt)*64 + lq*16 + lm)*8 + j  (p=r>>4, lm=r&15, kt=k>>5,
//   lq=(k>>3)&3, j=k&7). B-fragment load = base + lane*16B, one dwordx4.
// (Layout + GEMM consumption correctness-verified in R7: absmax 1.5e-5.)
__global__ __launch_bounds__(256) void normalize_kernel(const float* __restrict__ Ex,
                                                        const float* __restrict__ Ey,
                                                        u16* __restrict__ Xn,
                                                        u16* __restrict__ Ys,
                                                        float* __restrict__ out) {
    const int t = threadIdx.x;
    const int ln = t & 63;
    const int row = blockIdx.x * 4 + (t >> 6);
    const float* src = (blockIdx.y == 0) ? Ex : Ey;

    float4 v = *(const float4*)(src + (size_t)row * DIM + ln * 4);
    float s = fmaf(v.x, v.x, fmaf(v.y, v.y, fmaf(v.z, v.z, v.w * v.w)));
    #pragma unroll
    for (int m = 32; m >= 1; m >>= 1) s += __shfl_xor(s, m, 64);
    float inv = 1.0f / fmaxf(sqrtf(s), 1e-8f);

    ushort4 o;
    o.x = f32_to_bf16_rne(v.x * inv);
    o.y = f32_to_bf16_rne(v.y * inv);
    o.z = f32_to_bf16_rne(v.z * inv);
    o.w = f32_to_bf16_rne(v.w * inv);

    if (blockIdx.y == 0) {
        *(ushort4*)(Xn + (size_t)row * DIM + ln * 4) = o;
        if (ln == 0) out[row] = __uint_as_float(0x7f800000u);  // +inf
    } else {
        const int p = row >> 4;
        const int lm = row & 15;
        const int kt = ln >> 3;
        const int lq = (ln >> 1) & 3;
        const int j4 = (ln & 1) * 4;
        const size_t off = ((size_t)((p * NKB + kt) * 64 + lq * 16 + lm)) * 8 + j4;
        *(ushort4*)(Ys + off) = o;
    }
}

#define LOADB(dst, base, kt)                                                  \
    {                                                                         \
        _Pragma("unroll")                                                     \
        for (int cg = 0; cg < 4; ++cg)                                        \
            dst[cg] = *(const short8*)((base) + cg * 4096 + (kt) * 512);      \
    }

#define STEP(buf, kt)                                                         \
    {                                                                         \
        short8 a[4];                                                          \
        _Pragma("unroll")                                                     \
        for (int rg = 0; rg < 4; ++rg)                                        \
            a[rg] = *(const short8*)(&As[(kt)][aoff[rg]]);                    \
        _Pragma("unroll")                                                     \
        for (int rg = 0; rg < 4; ++rg)                                        \
            _Pragma("unroll")                                                 \
            for (int cg = 0; cg < 4; ++cg)                                    \
                acc[rg][cg] = __builtin_amdgcn_mfma_f32_16x16x32_bf16(        \
                    a[rg], buf[cg], acc[rg][cg], 0, 0, 0);                    \
    }

// Block = 128 rows x 512 cols. A (128x256, 64 KB) staged to LDS ONCE
// (xor-swizzled, conflict-free b128 reads), ONE barrier, then a 32-step
// K-stream with ZERO barriers: A from LDS, B direct from panel-layout Ys
// (L2-resident strip per the grid ordering) through a named 4-buffer
// register rotation (P,Q,R,S) with 2-step prefetch distance (~300 cyc,
// ~ L2 hit latency). ct loop is unroll-1 with a loop-carried B pointer so
// the scheduler CANNOT hoist loads across ct bodies (R7's unbounded
// 32-step region caused a 651 MB scratch spill).
// Grid: b&63 = row-tile (fixed A set per XCD), b>>6 = colgroup.
__global__ __launch_bounds__(256, 2) void gemm_min_kernel(const u16* __restrict__ Xn,
                                                          const u16* __restrict__ Ys,
                                                          float* __restrict__ out) {
    __shared__ u16 As[NKB][BM * BK];  // 64 KB, full-K A

    const int tid = threadIdx.x;
    const int w = tid >> 6;
    const int lane = tid & 63;
    const int wr = w >> 1;
    const int wc = w & 1;
    const int lq = lane >> 4;
    const int lm = lane & 15;
    const int swz = (lm >> 1) & 3;

    const int b = blockIdx.x;
    const int rowStart = (b & 63) * BM;
    const int colPanBase = (b >> 6) * 32 + wc * 4;  // first of this wave's B panels

    // --- A prologue: stage full-K A tile via async DMA, single barrier ---
    {
        const int s0 = w * 64 + lane;
        const int s1 = s0 + 256;
        const int r0 = s0 >> 2, p0 = (s0 & 3) ^ ((r0 >> 1) & 3);
        const int r1 = s1 >> 2, p1 = (s1 & 3) ^ ((r1 >> 1) & 3);
        const int go0 = r0 * DIM + p0 * 8;
        const int go1 = r1 * DIM + p1 * 8;
        const int lo0 = (w * 64) * 8;
        const int lo1 = (256 + w * 64) * 8;
        const u16* xb = Xn + (size_t)rowStart * DIM;
        #pragma unroll
        for (int kb = 0; kb < NKB; ++kb) {
            load16(xb + go0 + kb * BK, &As[kb][lo0]);
            load16(xb + go1 + kb * BK, &As[kb][lo1]);
        }
    }

    int aoff[4];
    #pragma unroll
    for (int rg = 0; rg < 4; ++rg)
        aoff[rg] = ((wr * 64 + rg * 16 + lm) * 4 + (lq ^ swz)) * 8;

    // B base pointer (loop-carried across ct; +32768 elements = +8 panels).
    const u16* ybase = Ys + (size_t)colPanBase * 4096 + lane * 8;

    floatx4 mn4[4], mx4[4];
    #pragma unroll
    for (int rg = 0; rg < 4; ++rg) {
        mn4[rg] = (floatx4){3.4e38f, 3.4e38f, 3.4e38f, 3.4e38f};
        mx4[rg] = (floatx4){-3.4e38f, -3.4e38f, -3.4e38f, -3.4e38f};
    }

    __syncthreads();  // the ONLY barrier: A tile ready

    short8 P[4], Q[4], R[4], S[4];
    LOADB(P, ybase, 0);  // ct=0, kt=0
    LOADB(Q, ybase, 1);  // ct=0, kt=1

    #pragma unroll 1
    for (int ct = 0; ct < NCT; ++ct) {
        const u16* ynext = (ct < NCT - 1) ? (ybase + 32768) : ybase;

        floatx4 acc[4][4];
        #pragma unroll
        for (int i = 0; i < 4; ++i)
            #pragma unroll
            for (int j = 0; j < 4; ++j)
                acc[i][j] = (floatx4){0.0f, 0.0f, 0.0f, 0.0f};

        // body 0: prefetch kt=2,3 ; compute kt=0,1
        LOADB(R, ybase, 2);
        LOADB(S, ybase, 3);
        STEP(P, 0);
        STEP(Q, 1);
        // body 1: prefetch kt=4,5 ; compute kt=2,3
        LOADB(P, ybase, 4);
        LOADB(Q, ybase, 5);
        STEP(R, 2);
        STEP(S, 3);
        // body 2: prefetch kt=6,7 ; compute kt=4,5
        LOADB(R, ybase, 6);
        LOADB(S, ybase, 7);
        STEP(P, 4);
        STEP(Q, 5);
        // body 3: prefetch next ct's kt=0,1 ; compute kt=6,7
        LOADB(P, ynext, 0);
        LOADB(Q, ynext, 1);
        STEP(R, 6);
        STEP(S, 7);

        // Fold this col-tile into register-carried row min/max.
        #pragma unroll
        for (int rg = 0; rg < 4; ++rg)
            #pragma unroll
            for (int cg = 0; cg < 4; ++cg)
                #pragma unroll
                for (int r = 0; r < 4; ++r) {
                    float m = acc[rg][cg][r];
                    mn4[rg][r] = fminf(mn4[rg][r], m);
                    mx4[rg][r] = fmaxf(mx4[rg][r], m);
                }

        ybase += 32768;  // loop-carried: blocks cross-ct hoisting
    }

    // Single epilogue: quad-lane reduce, eval C twice (quasiconcavity),
    // fire-and-forget atomicMin (no read guard -- R3 post-mortem).
    #pragma unroll
    for (int rg = 0; rg < 4; ++rg) {
        #pragma unroll
        for (int r = 0; r < 4; ++r) {
            float mn = mn4[rg][r];
            float mx = mx4[rg][r];
            #pragma unroll
            for (int mofs = 1; mofs < 16; mofs <<= 1) {
                mn = fminf(mn, __shfl_xor(mn, mofs, 64));
                mx = fmaxf(mx, __shfl_xor(mx, mofs, 64));
            }
            if (lm == 0) {
                float cmin = fminf(c_of_m(mn), c_of_m(mx));
                int row = rowStart + wr * 64 + rg * 16 + lq * 4 + r;
                atomicMinFloat(&out[row], cmin);
            }
        }
    }
}

extern "C" void kernel_launch(void* const* d_in, const int* in_sizes, int n_in,
                              void* d_out, int out_size, void* d_ws, size_t ws_size,
                              hipStream_t stream) {
    const float* Ex = (const float*)d_in[0];
    const float* Ey = (const float*)d_in[1];
    float* out = (float*)d_out;
    u16* Xn = (u16*)d_ws;                // 4 MB, row-major bf16
    u16* Ys = Xn + (size_t)NROWS * DIM;  // 4 MB, B-panel layout bf16

    hipLaunchKernelGGL(normalize_kernel, dim3(NROWS / 4, 2), dim3(256), 0, stream,
                       Ex, Ey, Xn, Ys, out);
    hipLaunchKernelGGL(gemm_min_kernel, dim3(64 * 16), dim3(256), 0, stream,
                       Xn, Ys, out);
}